// Round 2
// baseline (669.594 us; speedup 1.0000x reference)
//
#include <hip/hip_runtime.h>
#include <hip/hip_bf16.h>
#include <math.h>

#define NN 8192
#define DD 512
#define INV_T 14.285714285714286f   // 1/0.07 ; also the logits_max (diagonal) value
#define NWPR 128                     // 64-bit words per mask row (NN/64)

typedef __attribute__((ext_vector_type(8))) short s16x8;  // 8 bf16 = 4 VGPRs
typedef __attribute__((ext_vector_type(4))) float f32x4;

__device__ __forceinline__ unsigned short f32_to_bf16(float f) {
  unsigned int u = __float_as_uint(f);
  u += 0x7FFFu + ((u >> 16) & 1u);   // round-to-nearest-even
  return (unsigned short)(u >> 16);
}

__device__ __forceinline__ void async16(const void* g, void* l) {
  // 16B-wide global->LDS DMA; LDS dest must be wave-uniform base + lane*16
  __builtin_amdgcn_global_load_lds((__attribute__((address_space(1))) void*)(void*)g,
                                   (__attribute__((address_space(3))) void*)l,
                                   16, 0, 0);
}

// ---------------- Kernel A: normalize rows, emit bf16 ----------------
__global__ __launch_bounds__(256) void normalize_kernel(const float* __restrict__ f,
                                                        unsigned short* __restrict__ fnb) {
  const int wave = threadIdx.x >> 6;
  const int lane = threadIdx.x & 63;
  const int row  = blockIdx.x * 4 + wave;
  const float* src = f + (size_t)row * DD + lane * 8;
  float4 v0 = *(const float4*)src;
  float4 v1 = *(const float4*)(src + 4);
  float ss = v0.x*v0.x + v0.y*v0.y + v0.z*v0.z + v0.w*v0.w
           + v1.x*v1.x + v1.y*v1.y + v1.z*v1.z + v1.w*v1.w;
  #pragma unroll
  for (int o = 32; o; o >>= 1) ss += __shfl_xor(ss, o);
  const float r = 1.0f / fmaxf(sqrtf(ss), 1e-8f);
  ushort4 a, b;
  a.x = f32_to_bf16(v0.x * r); a.y = f32_to_bf16(v0.y * r);
  a.z = f32_to_bf16(v0.z * r); a.w = f32_to_bf16(v0.w * r);
  b.x = f32_to_bf16(v1.x * r); b.y = f32_to_bf16(v1.y * r);
  b.z = f32_to_bf16(v1.z * r); b.w = f32_to_bf16(v1.w * r);
  unsigned short* dst = fnb + (size_t)row * DD + lane * 8;
  *(ushort4*)dst = a;
  *(ushort4*)(dst + 4) = b;
}

// ---------------- Kernel P: pack masks to bitmasks (pure streaming) ----------------
// bit b of word w  <->  mask[w*64 + b] != 0   (natural order)
__global__ __launch_bounds__(256) void pack_kernel(const int* __restrict__ posm,
                                                   const int* __restrict__ negm,
                                                   unsigned long long* __restrict__ pb,
                                                   unsigned long long* __restrict__ nb) {
  const int lane = threadIdx.x & 63;
  const long long gw = (long long)((blockIdx.x * 256 + threadIdx.x) >> 6);
  const long long nwaves = (long long)((gridDim.x * 256) >> 6);
  const long long NW = (long long)NN * NN / 64;
  for (long long w0 = gw * 8; w0 < NW; w0 += nwaves * 8) {
    unsigned long long bp[8], bn[8];
    #pragma unroll
    for (int u = 0; u < 8; ++u) {
      const size_t idx = (size_t)(w0 + u) * 64 + lane;
      const int p = __builtin_nontemporal_load(posm + idx);
      const int n = __builtin_nontemporal_load(negm + idx);
      bp[u] = __ballot(p != 0);
      bn[u] = __ballot(n != 0);
    }
    if (lane == 0) {
      #pragma unroll
      for (int u = 0; u < 8; u += 2) {
        ulonglong2 vp; vp.x = bp[u]; vp.y = bp[u + 1];
        ulonglong2 vn; vn.x = bn[u]; vn.y = bn[u + 1];
        *(ulonglong2*)(pb + w0 + u) = vp;
        *(ulonglong2*)(nb + w0 + u) = vn;
      }
    }
  }
}

// ---------------- Kernel B: fused upper-tri sim tile + bitmask epilogue ----------------
// 128x128 tile per block, 4 waves each 64x64 (4x4 of 16x16x32 bf16 MFMA), BK=32.
// LDS chunk XOR-swizzle: position p of row holds global chunk (p ^ ((row>>1)&3)).
__global__ __launch_bounds__(256) void fused_kernel(const unsigned short* __restrict__ fnb,
                                                    const unsigned long long* __restrict__ pb,
                                                    const unsigned long long* __restrict__ nb,
                                                    float* __restrict__ Spos,
                                                    float* __restrict__ Sneg,
                                                    float* __restrict__ Pcnt) {
  // decode compact triangular block id -> (bi, bj), bi <= bj, 64x64 block grid
  const int bid = blockIdx.x;
  int bi = (int)(64.5 - sqrt(64.5 * 64.5 - 2.0 * (double)bid));
  while (64 * bi - bi * (bi - 1) / 2 > bid) --bi;
  while (64 * (bi + 1) - (bi + 1) * bi / 2 <= bid) ++bi;
  const int bj = bi + (bid - (64 * bi - bi * (bi - 1) / 2));
  const int I = bi * 128;
  const int J = bj * 128;

  const int tid  = threadIdx.x;
  const int wave = tid >> 6;
  const int lane = tid & 63;
  const int wm = wave >> 1;            // 0..1 row half
  const int wn = wave & 1;             // 0..1 col half
  const int q   = lane >> 4;           // 0..3
  const int c16 = lane & 15;           // 0..15

  __shared__ alignas(16) unsigned short lA[128 * 32];
  __shared__ alignas(16) unsigned short lB[128 * 32];

  f32x4 acc[4][4];
  const f32x4 z4 = {0.f, 0.f, 0.f, 0.f};
  #pragma unroll
  for (int mt = 0; mt < 4; ++mt)
    #pragma unroll
    for (int nt = 0; nt < 4; ++nt) acc[mt][nt] = z4;

  for (int kk = 0; kk < DD / 32; ++kk) {
    const int k0 = kk * 32;
    #pragma unroll
    for (int c = 0; c < 2; ++c) {
      const int fidx = tid + c * 256;        // 0..511 16B-chunks
      const int row  = fidx >> 2;
      const int p    = fidx & 3;
      const int csrc = (p ^ ((row >> 1) & 3)) & 3;   // XOR swizzle (global side only)
      async16(fnb + (size_t)(I + row) * DD + k0 + csrc * 8, (char*)lA + fidx * 16);
      async16(fnb + (size_t)(J + row) * DD + k0 + csrc * 8, (char*)lB + fidx * 16);
    }
    __syncthreads();   // compiler drains vmcnt before barrier -> LDS data ready

    s16x8 aF[4], bF[4];
    #pragma unroll
    for (int t = 0; t < 4; ++t) {
      const int arow = wm * 64 + t * 16 + c16;
      const int apos = (q ^ ((arow >> 1) & 3)) & 3;
      aF[t] = *(const s16x8*)((const char*)lA + arow * 64 + apos * 16);
      const int brow = wn * 64 + t * 16 + c16;
      const int bpos = (q ^ ((brow >> 1) & 3)) & 3;
      bF[t] = *(const s16x8*)((const char*)lB + brow * 64 + bpos * 16);
    }
    #pragma unroll
    for (int mt = 0; mt < 4; ++mt)
      #pragma unroll
      for (int nt = 0; nt < 4; ++nt)
        acc[mt][nt] = __builtin_amdgcn_mfma_f32_16x16x32_bf16(aF[mt], bF[nt], acc[mt][nt], 0, 0, 0);
    __syncthreads();   // protect LDS from next iteration's staging
  }

  // ---- epilogue: e = exp(sim - M); bitmask row sums (direct) + col sums (transposed) ----
  const bool offdiag = (bi != bj);
  const bool hasdiag = (bi == bj) && (wm == wn);
  const int jw = bj * 2 + wn;          // direct-pass column word index

  unsigned long long pT[4], nT[4];
  if (offdiag) {
    #pragma unroll
    for (int nt = 0; nt < 4; ++nt) {
      const int col = J + wn * 64 + nt * 16 + c16;
      const size_t tw = (size_t)col * NWPR + bi * 2 + wm;
      pT[nt] = pb[tw];
      nT[nt] = nb[tw];
    }
  }
  float tsp[4] = {0,0,0,0}, tsn[4] = {0,0,0,0};

  #pragma unroll
  for (int mt = 0; mt < 4; ++mt) {
    const int rbase = I + wm * 64 + mt * 16 + q * 4;   // + r
    unsigned long long pw[4], nw[4];
    #pragma unroll
    for (int r = 0; r < 4; ++r) {
      const size_t w = (size_t)(rbase + r) * NWPR + jw;
      pw[r] = pb[w];
      nw[r] = nb[w];
      if (hasdiag) {   // zero the self-contrast diagonal bit
        const unsigned long long m = ~(1ULL << (mt * 16 + q * 4 + r));
        pw[r] &= m;
        nw[r] &= m;
      }
    }
    float dsp[4] = {0,0,0,0}, dsn[4] = {0,0,0,0};
    #pragma unroll
    for (int nt = 0; nt < 4; ++nt) {
      float e[4];
      #pragma unroll
      for (int r = 0; r < 4; ++r)
        e[r] = __expf(acc[mt][nt][r] * INV_T - INV_T);
      const int bpos = nt * 16 + c16;
      #pragma unroll
      for (int r = 0; r < 4; ++r) {
        const float pf = (float)((pw[r] >> bpos) & 1ULL);
        const float nf = (float)((nw[r] >> bpos) & 1ULL);
        dsp[r] = fmaf(e[r], pf, dsp[r]);
        dsn[r] = fmaf(e[r], nf, dsn[r]);
      }
      if (offdiag) {   // sim(col,row) == sim(row,col)
        const int bt = mt * 16 + q * 4;
        #pragma unroll
        for (int r = 0; r < 4; ++r) {
          tsp[nt] = fmaf(e[r], (float)((pT[nt] >> (bt + r)) & 1ULL), tsp[nt]);
          tsn[nt] = fmaf(e[r], (float)((nT[nt] >> (bt + r)) & 1ULL), tsn[nt]);
        }
      }
    }
    // reduce over the 16 lanes holding this row's columns
    #pragma unroll
    for (int r = 0; r < 4; ++r) {
      float a = dsp[r], b = dsn[r];
      #pragma unroll
      for (int o = 1; o <= 8; o <<= 1) {
        a += __shfl_xor(a, o);
        b += __shfl_xor(b, o);
      }
      if (c16 == 0) {
        atomicAdd(&Spos[rbase + r], a);
        atomicAdd(&Sneg[rbase + r], b);
        atomicAdd(&Pcnt[rbase + r], (float)__popcll(pw[r]));
      }
    }
  }

  if (offdiag) {
    #pragma unroll
    for (int nt = 0; nt < 4; ++nt) {
      float a = tsp[nt], b = tsn[nt];
      a += __shfl_xor(a, 16); a += __shfl_xor(a, 32);
      b += __shfl_xor(b, 16); b += __shfl_xor(b, 32);
      if (q == 0) {
        const int col = J + wn * 64 + nt * 16 + c16;
        atomicAdd(&Spos[col], a);
        atomicAdd(&Sneg[col], b);
        atomicAdd(&Pcnt[col], (float)__popcll(pT[nt]));
      }
    }
  }
}

// ---------------- Kernel C: finalize ----------------
__global__ __launch_bounds__(256) void finalize_kernel(const float* __restrict__ Spos,
                                                       const float* __restrict__ Sneg,
                                                       const float* __restrict__ Pcnt,
                                                       float* __restrict__ out) {
  float local = 0.f;
  for (int i = threadIdx.x; i < NN; i += 256) {
    const float sp = Spos[i], sn = Sneg[i], pc = Pcnt[i];
    const float card = (pc == 0.f) ? 1.f : pc;
    // loss_i = -(sp - log(sn)*pc)/card
    local += (logf(sn) * pc - sp) / card;
  }
  #pragma unroll
  for (int o = 32; o; o >>= 1) local += __shfl_xor(local, o);
  __shared__ float red[4];
  if ((threadIdx.x & 63) == 0) red[threadIdx.x >> 6] = local;
  __syncthreads();
  if (threadIdx.x == 0)
    out[0] = (red[0] + red[1] + red[2] + red[3]) * (1.0f / (float)NN);
}

extern "C" void kernel_launch(void* const* d_in, const int* in_sizes, int n_in,
                              void* d_out, int out_size, void* d_ws, size_t ws_size,
                              hipStream_t stream) {
  const float* feat = (const float*)d_in[0];
  const int* posm   = (const int*)d_in[1];
  const int* negm   = (const int*)d_in[2];
  float* out = (float*)d_out;

  char* ws = (char*)d_ws;
  unsigned short* fnb = (unsigned short*)ws;                       // 8 MB
  unsigned long long* pbit = (unsigned long long*)(ws + (size_t)8 * 1024 * 1024);   // 8 MB
  unsigned long long* nbit = (unsigned long long*)(ws + (size_t)16 * 1024 * 1024);  // 8 MB
  float* Spos = (float*)(ws + (size_t)24 * 1024 * 1024);
  float* Sneg = Spos + NN;
  float* Pcnt = Sneg + NN;

  hipMemsetAsync(Spos, 0, 3 * NN * sizeof(float), stream);
  normalize_kernel<<<NN / 4, 256, 0, stream>>>(feat, fnb);
  pack_kernel<<<4096, 256, 0, stream>>>(posm, negm, pbit, nbit);
  fused_kernel<<<2080, 256, 0, stream>>>(fnb, pbit, nbit, Spos, Sneg, Pcnt);
  finalize_kernel<<<1, 256, 0, stream>>>(Spos, Sneg, Pcnt, out);
}

// Round 3
// 654.414 us; speedup vs baseline: 1.0232x; 1.0232x over previous
//
#include <hip/hip_runtime.h>
#include <hip/hip_bf16.h>
#include <math.h>

#define NN 8192
#define DD 512
#define INV_T 14.285714285714286f   // 1/0.07 ; also the logits_max (diagonal) value

typedef __attribute__((ext_vector_type(8))) short s16x8;  // 8 bf16 = 4 VGPRs
typedef __attribute__((ext_vector_type(4))) float f32x4;

__device__ __forceinline__ unsigned short f32_to_bf16(float f) {
  unsigned int u = __float_as_uint(f);
  u += 0x7FFFu + ((u >> 16) & 1u);   // round-to-nearest-even
  return (unsigned short)(u >> 16);
}

__device__ __forceinline__ void async16(const void* g, void* l) {
  // 16B-wide global->LDS DMA; LDS dest must be wave-uniform base + lane*16
  __builtin_amdgcn_global_load_lds((__attribute__((address_space(1))) void*)(void*)g,
                                   (__attribute__((address_space(3))) void*)l,
                                   16, 0, 0);
}

// ---------------- Kernel A: normalize rows, emit bf16 ----------------
__global__ __launch_bounds__(256) void normalize_kernel(const float* __restrict__ f,
                                                        unsigned short* __restrict__ fnb) {
  const int wave = threadIdx.x >> 6;
  const int lane = threadIdx.x & 63;
  const int row  = blockIdx.x * 4 + wave;
  const float* src = f + (size_t)row * DD + lane * 8;
  float4 v0 = *(const float4*)src;
  float4 v1 = *(const float4*)(src + 4);
  float ss = v0.x*v0.x + v0.y*v0.y + v0.z*v0.z + v0.w*v0.w
           + v1.x*v1.x + v1.y*v1.y + v1.z*v1.z + v1.w*v1.w;
  #pragma unroll
  for (int o = 32; o; o >>= 1) ss += __shfl_xor(ss, o);
  const float r = 1.0f / fmaxf(sqrtf(ss), 1e-8f);
  ushort4 a, b;
  a.x = f32_to_bf16(v0.x * r); a.y = f32_to_bf16(v0.y * r);
  a.z = f32_to_bf16(v0.z * r); a.w = f32_to_bf16(v0.w * r);
  b.x = f32_to_bf16(v1.x * r); b.y = f32_to_bf16(v1.y * r);
  b.z = f32_to_bf16(v1.z * r); b.w = f32_to_bf16(v1.w * r);
  unsigned short* dst = fnb + (size_t)row * DD + lane * 8;
  *(ushort4*)dst = a;
  *(ushort4*)(dst + 4) = b;
}

// ---------------- Kernel B: fused upper-tri sim tile + in-kernel mask pack ----------------
// 128x128 tile per block, 4 waves each 64x64 (4x4 of 16x16x32 bf16 MFMA), BK=32.
// Mask staging: each wave ballot-packs one (tile in {direct,transposed}, mask in {pos,neg})
// 128x128 int tile into 2KB of LDS via coalesced 256B loads. 536 MB read once chip-wide.
__global__ __launch_bounds__(256) void fused_kernel(const unsigned short* __restrict__ fnb,
                                                    const int* __restrict__ posm,
                                                    const int* __restrict__ negm,
                                                    float* __restrict__ Spos,
                                                    float* __restrict__ Sneg,
                                                    float* __restrict__ Pcnt) {
  // decode compact triangular block id -> (bi, bj), bi <= bj, 64x64 block grid
  const int bid = blockIdx.x;
  int bi = (int)(64.5 - sqrt(64.5 * 64.5 - 2.0 * (double)bid));
  while (64 * bi - bi * (bi - 1) / 2 > bid) --bi;
  while (64 * (bi + 1) - (bi + 1) * bi / 2 <= bid) ++bi;
  const int bj = bi + (bid - (64 * bi - bi * (bi - 1) / 2));
  const int I = bi * 128;
  const int J = bj * 128;
  const bool offdiag = (bi != bj);

  const int tid  = threadIdx.x;
  const int wave = tid >> 6;
  const int lane = tid & 63;
  const int wm = wave >> 1;            // 0..1 row half
  const int wn = wave & 1;             // 0..1 col half
  const int q   = lane >> 4;           // 0..3
  const int c16 = lane & 15;           // 0..15

  __shared__ alignas(16) unsigned short lA[128 * 32];
  __shared__ alignas(16) unsigned short lB[128 * 32];
  // bit-packed mask tiles: [mask sel][local row][64-col half]
  __shared__ alignas(16) unsigned long long mdir[2][128][2];  // rows I.., cols J..
  __shared__ alignas(16) unsigned long long mtr [2][128][2];  // rows J.., cols I..

  // ---- mask staging: wave -> (tile, mask) ----
  {
    const int tile = wave >> 1;        // 0 = direct, 1 = transposed
    const int msel = wave & 1;         // 0 = pos, 1 = neg
    const int R0 = tile ? J : I;
    const int C0 = tile ? I : J;
    const int* mb = msel ? negm : posm;
    unsigned long long (*dst)[2] = tile ? mtr[msel] : mdir[msel];
    if (!(tile && !offdiag)) {         // diag blocks: transposed tile unused
      for (int k = 0; k < 128; k += 8) {
        int v[16];
        #pragma unroll
        for (int u = 0; u < 16; ++u)
          v[u] = __builtin_nontemporal_load(
              mb + (size_t)(R0 + k + (u >> 1)) * NN + C0 + (u & 1) * 64 + lane);
        unsigned long long b[16];
        #pragma unroll
        for (int u = 0; u < 16; ++u) b[u] = __ballot(v[u] != 0);
        if (lane == 0) {
          #pragma unroll
          for (int u = 0; u < 16; u += 2) {
            ulonglong2 t; t.x = b[u]; t.y = b[u + 1];
            *(ulonglong2*)&dst[k + (u >> 1)][0] = t;
          }
        }
      }
    }
  }
  // no barrier needed here: first K-loop __syncthreads orders these LDS writes,
  // and only the (post-K-loop) epilogue reads them.

  f32x4 acc[4][4];
  const f32x4 z4 = {0.f, 0.f, 0.f, 0.f};
  #pragma unroll
  for (int mt = 0; mt < 4; ++mt)
    #pragma unroll
    for (int nt = 0; nt < 4; ++nt) acc[mt][nt] = z4;

  for (int kk = 0; kk < DD / 32; ++kk) {
    const int k0 = kk * 32;
    #pragma unroll
    for (int c = 0; c < 2; ++c) {
      const int fidx = tid + c * 256;        // 0..511 16B-chunks
      const int row  = fidx >> 2;
      const int p    = fidx & 3;
      const int csrc = (p ^ ((row >> 1) & 3)) & 3;   // XOR swizzle (global side only)
      async16(fnb + (size_t)(I + row) * DD + k0 + csrc * 8, (char*)lA + fidx * 16);
      async16(fnb + (size_t)(J + row) * DD + k0 + csrc * 8, (char*)lB + fidx * 16);
    }
    __syncthreads();   // compiler drains vmcnt before barrier -> LDS data ready

    s16x8 aF[4], bF[4];
    #pragma unroll
    for (int t = 0; t < 4; ++t) {
      const int arow = wm * 64 + t * 16 + c16;
      const int apos = (q ^ ((arow >> 1) & 3)) & 3;
      aF[t] = *(const s16x8*)((const char*)lA + arow * 64 + apos * 16);
      const int brow = wn * 64 + t * 16 + c16;
      const int bpos = (q ^ ((brow >> 1) & 3)) & 3;
      bF[t] = *(const s16x8*)((const char*)lB + brow * 64 + bpos * 16);
    }
    #pragma unroll
    for (int mt = 0; mt < 4; ++mt)
      #pragma unroll
      for (int nt = 0; nt < 4; ++nt)
        acc[mt][nt] = __builtin_amdgcn_mfma_f32_16x16x32_bf16(aF[mt], bF[nt], acc[mt][nt], 0, 0, 0);
    __syncthreads();   // protect LDS from next iteration's staging
  }

  // ---- epilogue: e = exp(sim - M); bitmask row sums (direct) + col sums (transposed) ----
  const bool hasdiag = (bi == bj) && (wm == wn);

  unsigned long long pT[4], nT[4];
  if (offdiag) {
    #pragma unroll
    for (int nt = 0; nt < 4; ++nt) {
      const int cl = wn * 64 + nt * 16 + c16;   // local row in transposed tile
      pT[nt] = mtr[0][cl][wm];
      nT[nt] = mtr[1][cl][wm];
    }
  }
  float tsp[4] = {0,0,0,0}, tsn[4] = {0,0,0,0};

  #pragma unroll
  for (int mt = 0; mt < 4; ++mt) {
    const int rl = wm * 64 + mt * 16 + q * 4;          // local row base
    const int rbase = I + rl;                          // global row base
    unsigned long long pw[4], nw[4];
    #pragma unroll
    for (int r = 0; r < 4; ++r) {
      pw[r] = mdir[0][rl + r][wn];
      nw[r] = mdir[1][rl + r][wn];
      if (hasdiag) {   // zero the self-contrast diagonal bit
        const unsigned long long m = ~(1ULL << (mt * 16 + q * 4 + r));
        pw[r] &= m;
        nw[r] &= m;
      }
    }
    float dsp[4] = {0,0,0,0}, dsn[4] = {0,0,0,0};
    #pragma unroll
    for (int nt = 0; nt < 4; ++nt) {
      float e[4];
      #pragma unroll
      for (int r = 0; r < 4; ++r)
        e[r] = __expf(acc[mt][nt][r] * INV_T - INV_T);
      const int bpos = nt * 16 + c16;
      #pragma unroll
      for (int r = 0; r < 4; ++r) {
        const float pf = (float)((pw[r] >> bpos) & 1ULL);
        const float nf = (float)((nw[r] >> bpos) & 1ULL);
        dsp[r] = fmaf(e[r], pf, dsp[r]);
        dsn[r] = fmaf(e[r], nf, dsn[r]);
      }
      if (offdiag) {   // sim(col,row) == sim(row,col)
        const int bt = mt * 16 + q * 4;
        #pragma unroll
        for (int r = 0; r < 4; ++r) {
          tsp[nt] = fmaf(e[r], (float)((pT[nt] >> (bt + r)) & 1ULL), tsp[nt]);
          tsn[nt] = fmaf(e[r], (float)((nT[nt] >> (bt + r)) & 1ULL), tsn[nt]);
        }
      }
    }
    // reduce over the 16 lanes holding this row's columns
    #pragma unroll
    for (int r = 0; r < 4; ++r) {
      float a = dsp[r], b = dsn[r];
      #pragma unroll
      for (int o = 1; o <= 8; o <<= 1) {
        a += __shfl_xor(a, o);
        b += __shfl_xor(b, o);
      }
      if (c16 == 0) {
        atomicAdd(&Spos[rbase + r], a);
        atomicAdd(&Sneg[rbase + r], b);
        atomicAdd(&Pcnt[rbase + r], (float)__popcll(pw[r]));
      }
    }
  }

  if (offdiag) {
    #pragma unroll
    for (int nt = 0; nt < 4; ++nt) {
      float a = tsp[nt], b = tsn[nt];
      a += __shfl_xor(a, 16); a += __shfl_xor(a, 32);
      b += __shfl_xor(b, 16); b += __shfl_xor(b, 32);
      if (q == 0) {
        const int col = J + wn * 64 + nt * 16 + c16;
        atomicAdd(&Spos[col], a);
        atomicAdd(&Sneg[col], b);
        atomicAdd(&Pcnt[col], (float)__popcll(pT[nt]));
      }
    }
  }
}

// ---------------- Kernel C: finalize ----------------
__global__ __launch_bounds__(256) void finalize_kernel(const float* __restrict__ Spos,
                                                       const float* __restrict__ Sneg,
                                                       const float* __restrict__ Pcnt,
                                                       float* __restrict__ out) {
  float local = 0.f;
  for (int i = threadIdx.x; i < NN; i += 256) {
    const float sp = Spos[i], sn = Sneg[i], pc = Pcnt[i];
    const float card = (pc == 0.f) ? 1.f : pc;
    // loss_i = -(sp - log(sn)*pc)/card
    local += (logf(sn) * pc - sp) / card;
  }
  #pragma unroll
  for (int o = 32; o; o >>= 1) local += __shfl_xor(local, o);
  __shared__ float red[4];
  if ((threadIdx.x & 63) == 0) red[threadIdx.x >> 6] = local;
  __syncthreads();
  if (threadIdx.x == 0)
    out[0] = (red[0] + red[1] + red[2] + red[3]) * (1.0f / (float)NN);
}

extern "C" void kernel_launch(void* const* d_in, const int* in_sizes, int n_in,
                              void* d_out, int out_size, void* d_ws, size_t ws_size,
                              hipStream_t stream) {
  const float* feat = (const float*)d_in[0];
  const int* posm   = (const int*)d_in[1];
  const int* negm   = (const int*)d_in[2];
  float* out = (float*)d_out;

  char* ws = (char*)d_ws;
  unsigned short* fnb = (unsigned short*)ws;                 // 8 MB
  float* Spos = (float*)(ws + (size_t)8 * 1024 * 1024);
  float* Sneg = Spos + NN;
  float* Pcnt = Sneg + NN;

  hipMemsetAsync(Spos, 0, 3 * NN * sizeof(float), stream);
  normalize_kernel<<<NN / 4, 256, 0, stream>>>(feat, fnb);
  fused_kernel<<<2080, 256, 0, stream>>>(fnb, posm, negm, Spos, Sneg, Pcnt);
  finalize_kernel<<<1, 256, 0, stream>>>(Spos, Sneg, Pcnt, out);
}